// Round 4
// baseline (396.461 us; speedup 1.0000x reference)
//
#include <hip/hip_runtime.h>
#include <stdint.h>

#define C_IN 64
#define C_OUT 128
#define NBUCK 65536

typedef unsigned int u32;
typedef unsigned long long u64;

// ---------- K1: compute compressed keys + bucket histogram ----------
__global__ void k1_keys(const int* __restrict__ grid, const int* __restrict__ batch,
                        const int* __restrict__ stride, int n,
                        u32* __restrict__ keys, u32* __restrict__ hist) {
  int i = blockIdx.x * blockDim.x + threadIdx.x;
  if (i >= n) return;
  int s = stride[0];
  u32 gx = (u32)(grid[3 * i] / s);
  u32 gy = (u32)(grid[3 * i + 1] / s);
  u32 gz = (u32)(grid[3 * i + 2] / s);
  u32 b = (u32)batch[i];
  u32 key = (b << 30) | (gz << 20) | (gy << 10) | gx;
  keys[i] = key;
  atomicAdd(&hist[key >> 16], 1u);
}

// ---------- K2: exclusive scan of 65536 bucket counts (1 block) ----------
__global__ void k2_scan(const u32* __restrict__ hist, u32* __restrict__ off,
                        u32* __restrict__ cursor) {
  __shared__ u32 part[1024];
  int t = threadIdx.x;
  u32 s = 0;
  for (int k = 0; k < 64; k++) s += hist[t * 64 + k];
  part[t] = s;
  __syncthreads();
  for (int d = 1; d < 1024; d <<= 1) {
    u32 v = (t >= d) ? part[t - d] : 0u;
    __syncthreads();
    part[t] += v;
    __syncthreads();
  }
  u32 run = part[t] - s;  // exclusive base for this thread's 64 buckets
  for (int k = 0; k < 64; k++) {
    u32 h = hist[t * 64 + k];
    off[t * 64 + k] = run;
    cursor[t * 64 + k] = run;
    run += h;
  }
  if (t == 1023) off[NBUCK] = run;  // == n
}

// ---------- K3: scatter (key,idx) pairs into buckets ----------
__global__ void k3_scatter(const u32* __restrict__ keys, u32* __restrict__ cursor,
                           u64* __restrict__ pairs, int n) {
  int i = blockIdx.x * blockDim.x + threadIdx.x;
  if (i >= n) return;
  u32 key = keys[i];
  u32 pos = atomicAdd(&cursor[key >> 16], 1u);
  pairs[pos] = ((u64)key << 32) | (u32)i;
}

// ---------- K4: per-bucket rank sort, one WAVE per bucket ----------
__global__ __launch_bounds__(256) void k4_sort(u64* __restrict__ pairs,
                                               const u32* __restrict__ off) {
  int wave = (blockIdx.x * blockDim.x + threadIdx.x) >> 6;
  int lane = threadIdx.x & 63;
  if (wave >= NBUCK) return;
  u32 lo = off[wave], hi = off[wave + 1];
  u32 k = hi - lo;
  if (k <= 1) return;
  if (k <= 64) {
    u64 v = (lane < (int)k) ? pairs[lo + lane] : ~0ull;
    int rank = 0;
    for (u32 j = 0; j < k; j++) {
      u64 o = __shfl(v, (int)j, 64);
      rank += (o < v) ? 1 : 0;
    }
    if (lane < (int)k) pairs[lo + rank] = v;
  } else if (lane == 0) {  // cold fallback, statistically never taken
    for (u32 i = lo + 1; i < hi; i++) {
      u64 v = pairs[i];
      u32 j = i;
      while (j > lo && pairs[j - 1] > v) { pairs[j] = pairs[j - 1]; j--; }
      pairs[j] = v;
    }
  }
}

// ---------- K5a: per-block head counts (4096 positions/block) ----------
__global__ void k5a_count(const u64* __restrict__ pairs, int n, u32* __restrict__ blockCnt) {
  __shared__ u32 part[256];
  int tid = threadIdx.x;
  int p0 = blockIdx.x * 4096 + tid * 16;
  u32 cnt = 0;
  u32 prevkey = (p0 > 0 && p0 < n) ? (u32)(pairs[p0 - 1] >> 32) : 0u;
  for (int r = 0; r < 16; r++) {
    int p = p0 + r;
    if (p >= n) break;
    u32 k = (u32)(pairs[p] >> 32);
    cnt += (p == 0) || (k != prevkey);
    prevkey = k;
  }
  part[tid] = cnt;
  __syncthreads();
  for (int d = 128; d > 0; d >>= 1) {
    if (tid < d) part[tid] += part[tid + d];
    __syncthreads();
  }
  if (tid == 0) blockCnt[blockIdx.x] = part[0];
}

// ---------- K5b: scan block head counts (1 block, nb<=256) ----------
__global__ void k5b_scanblocks(const u32* __restrict__ blockCnt, int nb,
                               u32* __restrict__ blockBase, u32* __restrict__ meta,
                               u32* __restrict__ segStart, int n) {
  __shared__ u32 part[256];
  int t = threadIdx.x;
  u32 v = (t < nb) ? blockCnt[t] : 0u;
  part[t] = v;
  __syncthreads();
  for (int d = 1; d < 256; d <<= 1) {
    u32 x = (t >= d) ? part[t - d] : 0u;
    __syncthreads();
    part[t] += x;
    __syncthreads();
  }
  if (t < nb) blockBase[t] = part[t] - v;
  if (t == 254) meta[1] = 0u;  // reset multi-cluster counter (runs before k5c)
  if (t == 255) {
    u32 total = part[255];
    meta[0] = total;           // number of unique segments
    segStart[total] = (u32)n;  // sentinel
  }
}

// ---------- K5c: assign ranks, write cluster ids (+multi flag), seg starts, grid/batch ----------
__global__ void k5c_assign(const u64* __restrict__ pairs, int n,
                           const u32* __restrict__ blockBase,
                           u32* __restrict__ segStart, u32* __restrict__ cluster,
                           float* __restrict__ out_grid, float* __restrict__ out_batch,
                           u32* __restrict__ meta, u32* __restrict__ multiList) {
  __shared__ u32 part[256];
  int tid = threadIdx.x;
  int p0 = blockIdx.x * 4096 + tid * 16;
  u32 cnt = 0;
  u32 prevkey = (p0 > 0 && p0 < n) ? (u32)(pairs[p0 - 1] >> 32) : 0u;
  for (int r = 0; r < 16; r++) {
    int p = p0 + r;
    if (p >= n) break;
    u32 k = (u32)(pairs[p] >> 32);
    cnt += (p == 0) || (k != prevkey);
    prevkey = k;
  }
  part[tid] = cnt;
  __syncthreads();
  for (int d = 1; d < 256; d <<= 1) {
    u32 x = (tid >= d) ? part[tid - d] : 0u;
    __syncthreads();
    part[tid] += x;
    __syncthreads();
  }
  u32 heads = blockBase[blockIdx.x] + part[tid] - cnt;
  prevkey = (p0 > 0 && p0 < n) ? (u32)(pairs[p0 - 1] >> 32) : 0u;
  for (int r = 0; r < 16; r++) {
    int p = p0 + r;
    if (p >= n) break;
    u64 cur = pairs[p];
    u32 k = (u32)(cur >> 32);
    bool head = (p == 0) || (k != prevkey);
    bool next_eq = (p + 1 < n) && ((u32)(pairs[p + 1] >> 32) == k);
    if (head) {
      segStart[heads] = (u32)p;
      out_grid[(size_t)heads * 3 + 0] = (float)(k & 0x3FFu);
      out_grid[(size_t)heads * 3 + 1] = (float)((k >> 10) & 0x3FFu);
      out_grid[(size_t)heads * 3 + 2] = (float)((k >> 20) & 0x3FFu);
      out_batch[heads] = (float)(k >> 30);
      heads++;
      if (next_eq) {  // multi-point cluster: record seg id for k8
        u32 slot = atomicAdd(&meta[1], 1u);
        multiList[slot] = heads - 1;
      }
    }
    u32 seg = heads - 1;
    bool prev_eq = (p > 0) && (prevkey == k);
    u32 multi = (next_eq || prev_eq) ? 0x80000000u : 0u;
    cluster[(u32)(cur & 0xFFFFFFFFu)] = seg | multi;
    prevkey = k;
  }
}

// ---------- K6: fused GEMM + scatter store for singleton clusters ----------
// launch_bounds(256,1): allow full VGPR budget so wreg[64] stays in registers.
__global__ __launch_bounds__(256, 1) void k6_gemm(
    const float* __restrict__ feat, const float* __restrict__ weight,
    const float* __restrict__ bias, const u32* __restrict__ cluster,
    float* __restrict__ out_feat, int n) {
  __shared__ float ldsF[32 * C_IN];
  __shared__ u32 ldsC[32];
  const int tid = threadIdx.x;
  const int lane = tid & 63;
  const int wid = tid >> 6;
  const int h = wid & 1;
  const int c = h * 64 + lane;  // output channel owned by this thread
  float wreg[C_IN];
  const float4* wrow = (const float4*)(weight + (size_t)c * C_IN);
#pragma unroll
  for (int q = 0; q < 16; q++) {
    float4 v = wrow[q];
    wreg[4 * q] = v.x; wreg[4 * q + 1] = v.y; wreg[4 * q + 2] = v.z; wreg[4 * q + 3] = v.w;
  }
  const float bc = bias[c];
  const int nch = (n + 31) >> 5;
  for (int ch = blockIdx.x; ch < nch; ch += gridDim.x) {
    const int base = ch << 5;
    __syncthreads();  // protect LDS from previous iteration readers
    if (base + 32 <= n) {
      const float4* src = (const float4*)(feat + (size_t)base * C_IN);
      ((float4*)ldsF)[tid] = src[tid];
      ((float4*)ldsF)[tid + 256] = src[tid + 256];
    } else {
      for (int t = tid; t < 32 * C_IN; t += 256) {
        int p = base + (t >> 6);
        ldsF[t] = (p < n) ? feat[(size_t)p * C_IN + (t & 63)] : 0.f;
      }
    }
    if (tid < 32) ldsC[tid] = (base + tid < n) ? cluster[base + tid] : 0x80000000u;
    __syncthreads();
    for (int j = (wid >> 1); j < 32; j += 2) {
      if (base + j >= n) break;
      u32 cl = ldsC[j];
      if (cl & 0x80000000u) continue;  // multi-point cluster: handled in k8
      const float4* f4 = (const float4*)(ldsF + j * C_IN);
      // 4 independent accumulator chains: 16 deps each, issue-bound not latency-bound
      float a0 = bc, a1 = 0.f, a2 = 0.f, a3 = 0.f;
#pragma unroll
      for (int q = 0; q < 4; q++) {
        float4 v0 = f4[4 * q + 0];
        float4 v1 = f4[4 * q + 1];
        float4 v2 = f4[4 * q + 2];
        float4 v3 = f4[4 * q + 3];
        a0 = fmaf(v0.x, wreg[16 * q + 0], a0);
        a0 = fmaf(v0.y, wreg[16 * q + 1], a0);
        a0 = fmaf(v0.z, wreg[16 * q + 2], a0);
        a0 = fmaf(v0.w, wreg[16 * q + 3], a0);
        a1 = fmaf(v1.x, wreg[16 * q + 4], a1);
        a1 = fmaf(v1.y, wreg[16 * q + 5], a1);
        a1 = fmaf(v1.z, wreg[16 * q + 6], a1);
        a1 = fmaf(v1.w, wreg[16 * q + 7], a1);
        a2 = fmaf(v2.x, wreg[16 * q + 8], a2);
        a2 = fmaf(v2.y, wreg[16 * q + 9], a2);
        a2 = fmaf(v2.z, wreg[16 * q + 10], a2);
        a2 = fmaf(v2.w, wreg[16 * q + 11], a2);
        a3 = fmaf(v3.x, wreg[16 * q + 12], a3);
        a3 = fmaf(v3.y, wreg[16 * q + 13], a3);
        a3 = fmaf(v3.z, wreg[16 * q + 14], a3);
        a3 = fmaf(v3.w, wreg[16 * q + 15], a3);
      }
      out_feat[(size_t)cl * C_OUT + c] = (a0 + a1) + (a2 + a3);
    }
  }
}

// ---------- K7: counts, coord means, invalid-tail zeros ----------
__global__ void k7_finalize(const u64* __restrict__ pairs, const u32* __restrict__ segStart,
                            const u32* __restrict__ meta, const float* __restrict__ coord,
                            float* __restrict__ out_feat, float* __restrict__ out_coord,
                            float* __restrict__ out_grid, float* __restrict__ out_batch,
                            float* __restrict__ out_counts, int n) {
  int t = blockIdx.x * blockDim.x + threadIdx.x;
  if (t >= n) return;
  u32 numSeg = meta[0];
  if ((u32)t < numSeg) {
    u32 st = segStart[t], en = segStart[t + 1];
    u32 cnt = en - st;
    out_counts[t] = (float)cnt;
    float sx = 0.f, sy = 0.f, sz = 0.f;
    for (u32 e = st; e < en; e++) {
      u32 idx = (u32)(pairs[e] & 0xFFFFFFFFu);
      sx += coord[(size_t)idx * 3 + 0];
      sy += coord[(size_t)idx * 3 + 1];
      sz += coord[(size_t)idx * 3 + 2];
    }
    float fc = (float)cnt;
    out_coord[(size_t)t * 3 + 0] = sx / fc;
    out_coord[(size_t)t * 3 + 1] = sy / fc;
    out_coord[(size_t)t * 3 + 2] = sz / fc;
  } else {
    out_counts[t] = 0.f;
    out_batch[t] = 0.f;
    out_coord[(size_t)t * 3 + 0] = 0.f;
    out_coord[(size_t)t * 3 + 1] = 0.f;
    out_coord[(size_t)t * 3 + 2] = 0.f;
    out_grid[(size_t)t * 3 + 0] = 0.f;
    out_grid[(size_t)t * 3 + 1] = 0.f;
    out_grid[(size_t)t * 3 + 2] = 0.f;
    for (int c = 0; c < C_OUT; c++) out_feat[(size_t)t * C_OUT + c] = 0.f;
  }
}

// ---------- K8: multi-point clusters — parallel matmul + max (1 block/cluster) ----------
__global__ __launch_bounds__(128) void k8_multi(
    const u64* __restrict__ pairs, const u32* __restrict__ segStart,
    const u32* __restrict__ meta, const u32* __restrict__ multiList,
    const float* __restrict__ feat, const float* __restrict__ weight,
    const float* __restrict__ bias, float* __restrict__ out_feat) {
  __shared__ float ldsF[C_IN];
  const int c = threadIdx.x;  // one output channel per thread (128 threads)
  float wreg[C_IN];
  const float4* wrow = (const float4*)(weight + (size_t)c * C_IN);
#pragma unroll
  for (int q = 0; q < 16; q++) {
    float4 v = wrow[q];
    wreg[4 * q] = v.x; wreg[4 * q + 1] = v.y; wreg[4 * q + 2] = v.z; wreg[4 * q + 3] = v.w;
  }
  const float bc = bias[c];
  const u32 nm = meta[1];
  for (u32 m = blockIdx.x; m < nm; m += gridDim.x) {
    u32 seg = multiList[m];
    u32 st = segStart[seg], en = segStart[seg + 1];
    float mx = -3.4e38f;
    for (u32 e = st; e < en; e++) {
      u32 idx = (u32)(pairs[e] & 0xFFFFFFFFu);
      __syncthreads();
      if (c < 16) ((float4*)ldsF)[c] = ((const float4*)(feat + (size_t)idx * C_IN))[c];
      __syncthreads();
      float d = bc;
#pragma unroll
      for (int q = 0; q < 16; q++) {
        float4 v = ((const float4*)ldsF)[q];
        d = fmaf(v.x, wreg[4 * q], d);
        d = fmaf(v.y, wreg[4 * q + 1], d);
        d = fmaf(v.z, wreg[4 * q + 2], d);
        d = fmaf(v.w, wreg[4 * q + 3], d);
      }
      mx = fmaxf(mx, d);
    }
    out_feat[(size_t)seg * C_OUT + c] = mx;
  }
}

extern "C" void kernel_launch(void* const* d_in, const int* in_sizes, int n_in,
                              void* d_out, int out_size, void* d_ws, size_t ws_size,
                              hipStream_t stream) {
  const float* feat = (const float*)d_in[0];
  const float* coord = (const float*)d_in[1];
  const float* weight = (const float*)d_in[2];
  const float* bias = (const float*)d_in[3];
  const int* grid = (const int*)d_in[4];
  const int* batch = (const int*)d_in[5];
  const int* stride = (const int*)d_in[6];
  const int n = in_sizes[0] / C_IN;

  float* out_feat = (float*)d_out;
  float* out_coord = out_feat + (size_t)n * C_OUT;
  float* out_grid = out_coord + (size_t)n * 3;
  float* out_batch = out_grid + (size_t)n * 3;
  float* out_counts = out_batch + n;

  u32* W = (u32*)d_ws;
  u32* hist = W;                   // 65536
  u32* cursor = W + 65536;         // 65536
  u32* off = W + 131072;           // 65537
  u32* meta = W + 196864;          // [0]=numSeg [1]=numMulti
  u32* blockCnt = W + 196992;      // up to 2048
  u32* blockBase = W + 199040;     // up to 2048
  u32* multiList = W + 201088;     // up to 65536 entries
  u32* keys = W + 270336;          // n
  u32* cluster = keys + n;         // n
  u32* segStart = cluster + n;     // n+1
  size_t pe = 270336 + 3 * (size_t)n + 2;
  pe &= ~(size_t)1;                // 8-byte align for u64
  u64* pairs = (u64*)(W + pe);     // n

  hipMemsetAsync(hist, 0, NBUCK * sizeof(u32), stream);
  int nb = (n + 255) / 256;
  k1_keys<<<nb, 256, 0, stream>>>(grid, batch, stride, n, keys, hist);
  k2_scan<<<1, 1024, 0, stream>>>(hist, off, cursor);
  k3_scatter<<<nb, 256, 0, stream>>>(keys, cursor, pairs, n);
  k4_sort<<<NBUCK / 4, 256, 0, stream>>>(pairs, off);  // one wave per bucket
  int nb5 = (n + 4095) / 4096;
  k5a_count<<<nb5, 256, 0, stream>>>(pairs, n, blockCnt);
  k5b_scanblocks<<<1, 256, 0, stream>>>(blockCnt, nb5, blockBase, meta, segStart, n);
  k5c_assign<<<nb5, 256, 0, stream>>>(pairs, n, blockBase, segStart, cluster, out_grid, out_batch,
                                      meta, multiList);
  k6_gemm<<<2048, 256, 0, stream>>>(feat, weight, bias, cluster, out_feat, n);
  k7_finalize<<<nb, 256, 0, stream>>>(pairs, segStart, meta, coord, out_feat, out_coord,
                                      out_grid, out_batch, out_counts, n);
  k8_multi<<<1024, 128, 0, stream>>>(pairs, segStart, meta, multiList, feat, weight, bias, out_feat);
}

// Round 5
// 295.998 us; speedup vs baseline: 1.3394x; 1.3394x over previous
//
#include <hip/hip_runtime.h>
#include <stdint.h>

#define C_IN 64
#define C_OUT 128
#define NBUCK 65536
#define TPTS 128  // points per k6 tile

typedef unsigned int u32;
typedef unsigned long long u64;

// ---------- K1: compute compressed keys + bucket histogram ----------
__global__ void k1_keys(const int* __restrict__ grid, const int* __restrict__ batch,
                        const int* __restrict__ stride, int n,
                        u32* __restrict__ keys, u32* __restrict__ hist) {
  int i = blockIdx.x * blockDim.x + threadIdx.x;
  if (i >= n) return;
  int s = stride[0];
  u32 gx = (u32)(grid[3 * i] / s);
  u32 gy = (u32)(grid[3 * i + 1] / s);
  u32 gz = (u32)(grid[3 * i + 2] / s);
  u32 b = (u32)batch[i];
  u32 key = (b << 30) | (gz << 20) | (gy << 10) | gx;
  keys[i] = key;
  atomicAdd(&hist[key >> 16], 1u);
}

// ---------- K2: exclusive scan of 65536 bucket counts (1 block) ----------
__global__ void k2_scan(const u32* __restrict__ hist, u32* __restrict__ off,
                        u32* __restrict__ cursor) {
  __shared__ u32 part[1024];
  int t = threadIdx.x;
  u32 s = 0;
  for (int k = 0; k < 64; k++) s += hist[t * 64 + k];
  part[t] = s;
  __syncthreads();
  for (int d = 1; d < 1024; d <<= 1) {
    u32 v = (t >= d) ? part[t - d] : 0u;
    __syncthreads();
    part[t] += v;
    __syncthreads();
  }
  u32 run = part[t] - s;  // exclusive base for this thread's 64 buckets
  for (int k = 0; k < 64; k++) {
    u32 h = hist[t * 64 + k];
    off[t * 64 + k] = run;
    cursor[t * 64 + k] = run;
    run += h;
  }
  if (t == 1023) off[NBUCK] = run;  // == n
}

// ---------- K3: scatter (key,idx) pairs into buckets ----------
__global__ void k3_scatter(const u32* __restrict__ keys, u32* __restrict__ cursor,
                           u64* __restrict__ pairs, int n) {
  int i = blockIdx.x * blockDim.x + threadIdx.x;
  if (i >= n) return;
  u32 key = keys[i];
  u32 pos = atomicAdd(&cursor[key >> 16], 1u);
  pairs[pos] = ((u64)key << 32) | (u32)i;
}

// ---------- K4: per-bucket rank sort, one WAVE per bucket ----------
__global__ __launch_bounds__(256) void k4_sort(u64* __restrict__ pairs,
                                               const u32* __restrict__ off) {
  int wave = (blockIdx.x * blockDim.x + threadIdx.x) >> 6;
  int lane = threadIdx.x & 63;
  if (wave >= NBUCK) return;
  u32 lo = off[wave], hi = off[wave + 1];
  u32 k = hi - lo;
  if (k <= 1) return;
  if (k <= 64) {
    u64 v = (lane < (int)k) ? pairs[lo + lane] : ~0ull;
    int rank = 0;
    for (u32 j = 0; j < k; j++) {
      u64 o = __shfl(v, (int)j, 64);
      rank += (o < v) ? 1 : 0;
    }
    if (lane < (int)k) pairs[lo + rank] = v;
  } else if (lane == 0) {  // cold fallback, statistically never taken
    for (u32 i = lo + 1; i < hi; i++) {
      u64 v = pairs[i];
      u32 j = i;
      while (j > lo && pairs[j - 1] > v) { pairs[j] = pairs[j - 1]; j--; }
      pairs[j] = v;
    }
  }
}

// ---------- K5a: per-block head counts (4096 positions/block) ----------
__global__ void k5a_count(const u64* __restrict__ pairs, int n, u32* __restrict__ blockCnt) {
  __shared__ u32 part[256];
  int tid = threadIdx.x;
  int p0 = blockIdx.x * 4096 + tid * 16;
  u32 cnt = 0;
  u32 prevkey = (p0 > 0 && p0 < n) ? (u32)(pairs[p0 - 1] >> 32) : 0u;
  for (int r = 0; r < 16; r++) {
    int p = p0 + r;
    if (p >= n) break;
    u32 k = (u32)(pairs[p] >> 32);
    cnt += (p == 0) || (k != prevkey);
    prevkey = k;
  }
  part[tid] = cnt;
  __syncthreads();
  for (int d = 128; d > 0; d >>= 1) {
    if (tid < d) part[tid] += part[tid + d];
    __syncthreads();
  }
  if (tid == 0) blockCnt[blockIdx.x] = part[0];
}

// ---------- K5b: scan block head counts (1 block, nb<=256) ----------
__global__ void k5b_scanblocks(const u32* __restrict__ blockCnt, int nb,
                               u32* __restrict__ blockBase, u32* __restrict__ meta,
                               u32* __restrict__ segStart, int n) {
  __shared__ u32 part[256];
  int t = threadIdx.x;
  u32 v = (t < nb) ? blockCnt[t] : 0u;
  part[t] = v;
  __syncthreads();
  for (int d = 1; d < 256; d <<= 1) {
    u32 x = (t >= d) ? part[t - d] : 0u;
    __syncthreads();
    part[t] += x;
    __syncthreads();
  }
  if (t < nb) blockBase[t] = part[t] - v;
  if (t == 254) meta[1] = 0u;  // reset multi-cluster counter (runs before k5c)
  if (t == 255) {
    u32 total = part[255];
    meta[0] = total;           // number of unique segments
    segStart[total] = (u32)n;  // sentinel
  }
}

// ---------- K5c: assign ranks, write cluster ids (+multi flag), seg starts, grid/batch ----------
__global__ void k5c_assign(const u64* __restrict__ pairs, int n,
                           const u32* __restrict__ blockBase,
                           u32* __restrict__ segStart, u32* __restrict__ cluster,
                           float* __restrict__ out_grid, float* __restrict__ out_batch,
                           u32* __restrict__ meta, u32* __restrict__ multiList) {
  __shared__ u32 part[256];
  int tid = threadIdx.x;
  int p0 = blockIdx.x * 4096 + tid * 16;
  u32 cnt = 0;
  u32 prevkey = (p0 > 0 && p0 < n) ? (u32)(pairs[p0 - 1] >> 32) : 0u;
  for (int r = 0; r < 16; r++) {
    int p = p0 + r;
    if (p >= n) break;
    u32 k = (u32)(pairs[p] >> 32);
    cnt += (p == 0) || (k != prevkey);
    prevkey = k;
  }
  part[tid] = cnt;
  __syncthreads();
  for (int d = 1; d < 256; d <<= 1) {
    u32 x = (tid >= d) ? part[tid - d] : 0u;
    __syncthreads();
    part[tid] += x;
    __syncthreads();
  }
  u32 heads = blockBase[blockIdx.x] + part[tid] - cnt;
  prevkey = (p0 > 0 && p0 < n) ? (u32)(pairs[p0 - 1] >> 32) : 0u;
  for (int r = 0; r < 16; r++) {
    int p = p0 + r;
    if (p >= n) break;
    u64 cur = pairs[p];
    u32 k = (u32)(cur >> 32);
    bool head = (p == 0) || (k != prevkey);
    bool next_eq = (p + 1 < n) && ((u32)(pairs[p + 1] >> 32) == k);
    if (head) {
      segStart[heads] = (u32)p;
      out_grid[(size_t)heads * 3 + 0] = (float)(k & 0x3FFu);
      out_grid[(size_t)heads * 3 + 1] = (float)((k >> 10) & 0x3FFu);
      out_grid[(size_t)heads * 3 + 2] = (float)((k >> 20) & 0x3FFu);
      out_batch[heads] = (float)(k >> 30);
      heads++;
      if (next_eq) {  // multi-point cluster: record seg id for k8
        u32 slot = atomicAdd(&meta[1], 1u);
        multiList[slot] = heads - 1;
      }
    }
    u32 seg = heads - 1;
    bool prev_eq = (p > 0) && (prevkey == k);
    u32 multi = (next_eq || prev_eq) ? 0x80000000u : 0u;
    cluster[(u32)(cur & 0xFFFFFFFFu)] = seg | multi;
    prevkey = k;
  }
}

// ---------- K6: register-tiled GEMM (128 pts x 128 ch per block) + scatter ----------
// fl[k][p], wl[k][c] both in LDS (transposed); thread tile 8 pts x 8 ch.
__global__ __launch_bounds__(256) void k6_gemm(
    const float* __restrict__ feat, const float* __restrict__ weight,
    const float* __restrict__ bias, const u32* __restrict__ cluster,
    float* __restrict__ out_feat, int n) {
  __shared__ float fl[C_IN * TPTS];   // 32 KB  [k][p]
  __shared__ float wl[C_IN * C_OUT];  // 32 KB  [k][c]
  __shared__ u32 ldsC[TPTS];
  const int tid = threadIdx.x;
  const int cg = tid & 15;   // channel group: channels cg*8 .. +7
  const int pg = tid >> 4;   // point group:   points  pg*8 .. +7

  // one-time: stage W transposed. thread owns c=tid>>1, k-half=(tid&1)*32.
  // ds_write pattern: even/odd lanes 2-way bank alias only (free).
  {
    int c = tid >> 1;
    int kh = (tid & 1) * 32;
    const float4* src = (const float4*)(weight + (size_t)c * C_IN + kh);
#pragma unroll
    for (int q = 0; q < 8; q++) {
      float4 v = src[q];
      int k = kh + q * 4;
      wl[(k + 0) * C_OUT + c] = v.x;
      wl[(k + 1) * C_OUT + c] = v.y;
      wl[(k + 2) * C_OUT + c] = v.z;
      wl[(k + 3) * C_OUT + c] = v.w;
    }
  }
  float breg[8];
#pragma unroll
  for (int j = 0; j < 8; j++) breg[j] = bias[cg * 8 + j];

  const int ntile = (n + TPTS - 1) / TPTS;
  for (int t = blockIdx.x; t < ntile; t += gridDim.x) {
    const int base = t * TPTS;
    __syncthreads();  // protect LDS from previous tile readers
    // stage feat transposed: thread owns p=tid>>1, k-half=(tid&1)*32
    {
      int p = tid >> 1;
      int kh = (tid & 1) * 32;
      int gp = base + p;
      if (gp < n) {
        const float4* src = (const float4*)(feat + (size_t)gp * C_IN + kh);
#pragma unroll
        for (int q = 0; q < 8; q++) {
          float4 v = src[q];
          int k = kh + q * 4;
          fl[(k + 0) * TPTS + p] = v.x;
          fl[(k + 1) * TPTS + p] = v.y;
          fl[(k + 2) * TPTS + p] = v.z;
          fl[(k + 3) * TPTS + p] = v.w;
        }
      } else {
#pragma unroll
        for (int q = 0; q < 32; q++) fl[(kh + q) * TPTS + p] = 0.f;
      }
      if (tid < TPTS) ldsC[tid] = (base + tid < n) ? cluster[base + tid] : 0x80000000u;
    }
    __syncthreads();

    float acc[8][8];
#pragma unroll
    for (int i = 0; i < 8; i++)
#pragma unroll
      for (int j = 0; j < 8; j++) acc[i][j] = 0.f;

#pragma unroll 2
    for (int k = 0; k < C_IN; k++) {
      float4 f0 = *(const float4*)(fl + k * TPTS + pg * 8);
      float4 f1 = *(const float4*)(fl + k * TPTS + pg * 8 + 4);
      float4 w0 = *(const float4*)(wl + k * C_OUT + cg * 8);
      float4 w1 = *(const float4*)(wl + k * C_OUT + cg * 8 + 4);
      float fv[8] = {f0.x, f0.y, f0.z, f0.w, f1.x, f1.y, f1.z, f1.w};
      float wv[8] = {w0.x, w0.y, w0.z, w0.w, w1.x, w1.y, w1.z, w1.w};
#pragma unroll
      for (int i = 0; i < 8; i++)
#pragma unroll
        for (int j = 0; j < 8; j++) acc[i][j] = fmaf(fv[i], wv[j], acc[i][j]);
    }

    // writeout: 16 lanes (cg 0..15) cover one 512B point row contiguously
#pragma unroll
    for (int i = 0; i < 8; i++) {
      int p = pg * 8 + i;
      u32 cl = ldsC[p];
      if (cl & 0x80000000u) continue;  // multi-point (k8) or tail
      float4 o0 = {acc[i][0] + breg[0], acc[i][1] + breg[1],
                   acc[i][2] + breg[2], acc[i][3] + breg[3]};
      float4 o1 = {acc[i][4] + breg[4], acc[i][5] + breg[5],
                   acc[i][6] + breg[6], acc[i][7] + breg[7]};
      float4* dst = (float4*)(out_feat + (size_t)cl * C_OUT + cg * 8);
      dst[0] = o0;
      dst[1] = o1;
    }
  }
}

// ---------- K7: counts, coord means, invalid-tail zeros ----------
__global__ void k7_finalize(const u64* __restrict__ pairs, const u32* __restrict__ segStart,
                            const u32* __restrict__ meta, const float* __restrict__ coord,
                            float* __restrict__ out_feat, float* __restrict__ out_coord,
                            float* __restrict__ out_grid, float* __restrict__ out_batch,
                            float* __restrict__ out_counts, int n) {
  int t = blockIdx.x * blockDim.x + threadIdx.x;
  if (t >= n) return;
  u32 numSeg = meta[0];
  if ((u32)t < numSeg) {
    u32 st = segStart[t], en = segStart[t + 1];
    u32 cnt = en - st;
    out_counts[t] = (float)cnt;
    float sx = 0.f, sy = 0.f, sz = 0.f;
    for (u32 e = st; e < en; e++) {
      u32 idx = (u32)(pairs[e] & 0xFFFFFFFFu);
      sx += coord[(size_t)idx * 3 + 0];
      sy += coord[(size_t)idx * 3 + 1];
      sz += coord[(size_t)idx * 3 + 2];
    }
    float fc = (float)cnt;
    out_coord[(size_t)t * 3 + 0] = sx / fc;
    out_coord[(size_t)t * 3 + 1] = sy / fc;
    out_coord[(size_t)t * 3 + 2] = sz / fc;
  } else {
    out_counts[t] = 0.f;
    out_batch[t] = 0.f;
    out_coord[(size_t)t * 3 + 0] = 0.f;
    out_coord[(size_t)t * 3 + 1] = 0.f;
    out_coord[(size_t)t * 3 + 2] = 0.f;
    out_grid[(size_t)t * 3 + 0] = 0.f;
    out_grid[(size_t)t * 3 + 1] = 0.f;
    out_grid[(size_t)t * 3 + 2] = 0.f;
    for (int c = 0; c < C_OUT; c++) out_feat[(size_t)t * C_OUT + c] = 0.f;
  }
}

// ---------- K8: multi-point clusters — parallel matmul + max (1 block/cluster) ----------
__global__ __launch_bounds__(128) void k8_multi(
    const u64* __restrict__ pairs, const u32* __restrict__ segStart,
    const u32* __restrict__ meta, const u32* __restrict__ multiList,
    const float* __restrict__ feat, const float* __restrict__ weight,
    const float* __restrict__ bias, float* __restrict__ out_feat) {
  __shared__ float ldsF[C_IN];
  const int c = threadIdx.x;  // one output channel per thread (128 threads)
  float wreg[C_IN];
  const float4* wrow = (const float4*)(weight + (size_t)c * C_IN);
#pragma unroll
  for (int q = 0; q < 16; q++) {
    float4 v = wrow[q];
    wreg[4 * q] = v.x; wreg[4 * q + 1] = v.y; wreg[4 * q + 2] = v.z; wreg[4 * q + 3] = v.w;
  }
  const float bc = bias[c];
  const u32 nm = meta[1];
  for (u32 m = blockIdx.x; m < nm; m += gridDim.x) {
    u32 seg = multiList[m];
    u32 st = segStart[seg], en = segStart[seg + 1];
    float mx = -3.4e38f;
    for (u32 e = st; e < en; e++) {
      u32 idx = (u32)(pairs[e] & 0xFFFFFFFFu);
      __syncthreads();
      if (c < 16) ((float4*)ldsF)[c] = ((const float4*)(feat + (size_t)idx * C_IN))[c];
      __syncthreads();
      float d = bc;
#pragma unroll
      for (int q = 0; q < 16; q++) {
        float4 v = ((const float4*)ldsF)[q];
        d = fmaf(v.x, wreg[4 * q], d);
        d = fmaf(v.y, wreg[4 * q + 1], d);
        d = fmaf(v.z, wreg[4 * q + 2], d);
        d = fmaf(v.w, wreg[4 * q + 3], d);
      }
      mx = fmaxf(mx, d);
    }
    out_feat[(size_t)seg * C_OUT + c] = mx;
  }
}

extern "C" void kernel_launch(void* const* d_in, const int* in_sizes, int n_in,
                              void* d_out, int out_size, void* d_ws, size_t ws_size,
                              hipStream_t stream) {
  const float* feat = (const float*)d_in[0];
  const float* coord = (const float*)d_in[1];
  const float* weight = (const float*)d_in[2];
  const float* bias = (const float*)d_in[3];
  const int* grid = (const int*)d_in[4];
  const int* batch = (const int*)d_in[5];
  const int* stride = (const int*)d_in[6];
  const int n = in_sizes[0] / C_IN;

  float* out_feat = (float*)d_out;
  float* out_coord = out_feat + (size_t)n * C_OUT;
  float* out_grid = out_coord + (size_t)n * 3;
  float* out_batch = out_grid + (size_t)n * 3;
  float* out_counts = out_batch + n;

  u32* W = (u32*)d_ws;
  u32* hist = W;                   // 65536
  u32* cursor = W + 65536;         // 65536
  u32* off = W + 131072;           // 65537
  u32* meta = W + 196864;          // [0]=numSeg [1]=numMulti
  u32* blockCnt = W + 196992;      // up to 2048
  u32* blockBase = W + 199040;     // up to 2048
  u32* multiList = W + 201088;     // up to 65536 entries
  u32* keys = W + 270336;          // n
  u32* cluster = keys + n;         // n
  u32* segStart = cluster + n;     // n+1
  size_t pe = 270336 + 3 * (size_t)n + 2;
  pe &= ~(size_t)1;                // 8-byte align for u64
  u64* pairs = (u64*)(W + pe);     // n

  hipMemsetAsync(hist, 0, NBUCK * sizeof(u32), stream);
  int nb = (n + 255) / 256;
  k1_keys<<<nb, 256, 0, stream>>>(grid, batch, stride, n, keys, hist);
  k2_scan<<<1, 1024, 0, stream>>>(hist, off, cursor);
  k3_scatter<<<nb, 256, 0, stream>>>(keys, cursor, pairs, n);
  k4_sort<<<NBUCK / 4, 256, 0, stream>>>(pairs, off);  // one wave per bucket
  int nb5 = (n + 4095) / 4096;
  k5a_count<<<nb5, 256, 0, stream>>>(pairs, n, blockCnt);
  k5b_scanblocks<<<1, 256, 0, stream>>>(blockCnt, nb5, blockBase, meta, segStart, n);
  k5c_assign<<<nb5, 256, 0, stream>>>(pairs, n, blockBase, segStart, cluster, out_grid, out_batch,
                                      meta, multiList);
  k6_gemm<<<2048, 256, 0, stream>>>(feat, weight, bias, cluster, out_feat, n);
  k7_finalize<<<nb, 256, 0, stream>>>(pairs, segStart, meta, coord, out_feat, out_coord,
                                      out_grid, out_batch, out_counts, n);
  k8_multi<<<1024, 128, 0, stream>>>(pairs, segStart, meta, multiList, feat, weight, bias, out_feat);
}

// Round 6
// 294.884 us; speedup vs baseline: 1.3445x; 1.0038x over previous
//
#include <hip/hip_runtime.h>
#include <stdint.h>

#define C_IN 64
#define C_OUT 128
#define NBUCK 65536
#define TPTS 128  // points per k6 tile

typedef unsigned int u32;
typedef unsigned long long u64;

// ---------- K0: zero the bucket histogram (replaces pathological graph-captured memset) ----------
__global__ void k0_zero(uint4* __restrict__ hist4) {
  int i = blockIdx.x * blockDim.x + threadIdx.x;
  hist4[i] = make_uint4(0u, 0u, 0u, 0u);
}

// ---------- K1: compute compressed keys + bucket histogram ----------
__global__ void k1_keys(const int* __restrict__ grid, const int* __restrict__ batch,
                        const int* __restrict__ stride, int n,
                        u32* __restrict__ keys, u32* __restrict__ hist) {
  int i = blockIdx.x * blockDim.x + threadIdx.x;
  if (i >= n) return;
  int s = stride[0];
  u32 gx = (u32)(grid[3 * i] / s);
  u32 gy = (u32)(grid[3 * i + 1] / s);
  u32 gz = (u32)(grid[3 * i + 2] / s);
  u32 b = (u32)batch[i];
  u32 key = (b << 30) | (gz << 20) | (gy << 10) | gx;
  keys[i] = key;
  atomicAdd(&hist[key >> 16], 1u);
}

// ---------- K2: exclusive scan of 65536 bucket counts (1 block) ----------
__global__ void k2_scan(const u32* __restrict__ hist, u32* __restrict__ off,
                        u32* __restrict__ cursor) {
  __shared__ u32 part[1024];
  int t = threadIdx.x;
  u32 s = 0;
  for (int k = 0; k < 64; k++) s += hist[t * 64 + k];
  part[t] = s;
  __syncthreads();
  for (int d = 1; d < 1024; d <<= 1) {
    u32 v = (t >= d) ? part[t - d] : 0u;
    __syncthreads();
    part[t] += v;
    __syncthreads();
  }
  u32 run = part[t] - s;  // exclusive base for this thread's 64 buckets
  for (int k = 0; k < 64; k++) {
    u32 h = hist[t * 64 + k];
    off[t * 64 + k] = run;
    cursor[t * 64 + k] = run;
    run += h;
  }
  if (t == 1023) off[NBUCK] = run;  // == n
}

// ---------- K3: scatter (key,idx) pairs into buckets ----------
__global__ void k3_scatter(const u32* __restrict__ keys, u32* __restrict__ cursor,
                           u64* __restrict__ pairs, int n) {
  int i = blockIdx.x * blockDim.x + threadIdx.x;
  if (i >= n) return;
  u32 key = keys[i];
  u32 pos = atomicAdd(&cursor[key >> 16], 1u);
  pairs[pos] = ((u64)key << 32) | (u32)i;
}

// ---------- K4: per-bucket rank sort, one WAVE per bucket ----------
__global__ __launch_bounds__(256) void k4_sort(u64* __restrict__ pairs,
                                               const u32* __restrict__ off) {
  int wave = (blockIdx.x * blockDim.x + threadIdx.x) >> 6;
  int lane = threadIdx.x & 63;
  if (wave >= NBUCK) return;
  u32 lo = off[wave], hi = off[wave + 1];
  u32 k = hi - lo;
  if (k <= 1) return;
  if (k <= 64) {
    u64 v = (lane < (int)k) ? pairs[lo + lane] : ~0ull;
    int rank = 0;
    for (u32 j = 0; j < k; j++) {
      u64 o = __shfl(v, (int)j, 64);
      rank += (o < v) ? 1 : 0;
    }
    if (lane < (int)k) pairs[lo + rank] = v;
  } else if (lane == 0) {  // cold fallback, statistically never taken
    for (u32 i = lo + 1; i < hi; i++) {
      u64 v = pairs[i];
      u32 j = i;
      while (j > lo && pairs[j - 1] > v) { pairs[j] = pairs[j - 1]; j--; }
      pairs[j] = v;
    }
  }
}

// ---------- K5a: per-block head counts (4096 positions/block) ----------
__global__ void k5a_count(const u64* __restrict__ pairs, int n, u32* __restrict__ blockCnt) {
  __shared__ u32 part[256];
  int tid = threadIdx.x;
  int p0 = blockIdx.x * 4096 + tid * 16;
  u32 cnt = 0;
  u32 prevkey = (p0 > 0 && p0 < n) ? (u32)(pairs[p0 - 1] >> 32) : 0u;
  for (int r = 0; r < 16; r++) {
    int p = p0 + r;
    if (p >= n) break;
    u32 k = (u32)(pairs[p] >> 32);
    cnt += (p == 0) || (k != prevkey);
    prevkey = k;
  }
  part[tid] = cnt;
  __syncthreads();
  for (int d = 128; d > 0; d >>= 1) {
    if (tid < d) part[tid] += part[tid + d];
    __syncthreads();
  }
  if (tid == 0) blockCnt[blockIdx.x] = part[0];
}

// ---------- K5b: scan block head counts (1 block, nb<=256) ----------
__global__ void k5b_scanblocks(const u32* __restrict__ blockCnt, int nb,
                               u32* __restrict__ blockBase, u32* __restrict__ meta,
                               u32* __restrict__ segStart, int n) {
  __shared__ u32 part[256];
  int t = threadIdx.x;
  u32 v = (t < nb) ? blockCnt[t] : 0u;
  part[t] = v;
  __syncthreads();
  for (int d = 1; d < 256; d <<= 1) {
    u32 x = (t >= d) ? part[t - d] : 0u;
    __syncthreads();
    part[t] += x;
    __syncthreads();
  }
  if (t < nb) blockBase[t] = part[t] - v;
  if (t == 254) meta[1] = 0u;  // reset multi-cluster counter (runs before k5c)
  if (t == 255) {
    u32 total = part[255];
    meta[0] = total;           // number of unique segments
    segStart[total] = (u32)n;  // sentinel
  }
}

// ---------- K5c: assign ranks, write cluster ids (+multi flag), seg starts, grid/batch ----------
__global__ void k5c_assign(const u64* __restrict__ pairs, int n,
                           const u32* __restrict__ blockBase,
                           u32* __restrict__ segStart, u32* __restrict__ cluster,
                           float* __restrict__ out_grid, float* __restrict__ out_batch,
                           u32* __restrict__ meta, u32* __restrict__ multiList) {
  __shared__ u32 part[256];
  int tid = threadIdx.x;
  int p0 = blockIdx.x * 4096 + tid * 16;
  u32 cnt = 0;
  u32 prevkey = (p0 > 0 && p0 < n) ? (u32)(pairs[p0 - 1] >> 32) : 0u;
  for (int r = 0; r < 16; r++) {
    int p = p0 + r;
    if (p >= n) break;
    u32 k = (u32)(pairs[p] >> 32);
    cnt += (p == 0) || (k != prevkey);
    prevkey = k;
  }
  part[tid] = cnt;
  __syncthreads();
  for (int d = 1; d < 256; d <<= 1) {
    u32 x = (tid >= d) ? part[tid - d] : 0u;
    __syncthreads();
    part[tid] += x;
    __syncthreads();
  }
  u32 heads = blockBase[blockIdx.x] + part[tid] - cnt;
  prevkey = (p0 > 0 && p0 < n) ? (u32)(pairs[p0 - 1] >> 32) : 0u;
  for (int r = 0; r < 16; r++) {
    int p = p0 + r;
    if (p >= n) break;
    u64 cur = pairs[p];
    u32 k = (u32)(cur >> 32);
    bool head = (p == 0) || (k != prevkey);
    bool next_eq = (p + 1 < n) && ((u32)(pairs[p + 1] >> 32) == k);
    if (head) {
      segStart[heads] = (u32)p;
      out_grid[(size_t)heads * 3 + 0] = (float)(k & 0x3FFu);
      out_grid[(size_t)heads * 3 + 1] = (float)((k >> 10) & 0x3FFu);
      out_grid[(size_t)heads * 3 + 2] = (float)((k >> 20) & 0x3FFu);
      out_batch[heads] = (float)(k >> 30);
      heads++;
      if (next_eq) {  // multi-point cluster: record seg id for k8
        u32 slot = atomicAdd(&meta[1], 1u);
        multiList[slot] = heads - 1;
      }
    }
    u32 seg = heads - 1;
    bool prev_eq = (p > 0) && (prevkey == k);
    u32 multi = (next_eq || prev_eq) ? 0x80000000u : 0u;
    cluster[(u32)(cur & 0xFFFFFFFFu)] = seg | multi;
    prevkey = k;
  }
}

// ---------- K6: register-tiled GEMM (128 pts x 128 ch per block) + scatter ----------
__global__ __launch_bounds__(256) void k6_gemm(
    const float* __restrict__ feat, const float* __restrict__ weight,
    const float* __restrict__ bias, const u32* __restrict__ cluster,
    float* __restrict__ out_feat, int n) {
  __shared__ float fl[C_IN * TPTS];   // 32 KB  [k][p]
  __shared__ float wl[C_IN * C_OUT];  // 32 KB  [k][c]
  __shared__ u32 ldsC[TPTS];
  const int tid = threadIdx.x;
  const int cg = tid & 15;   // channel group: channels cg*8 .. +7
  const int pg = tid >> 4;   // point group:   points  pg*8 .. +7

  // one-time: stage W transposed. thread owns c=tid>>1, k-half=(tid&1)*32.
  {
    int c = tid >> 1;
    int kh = (tid & 1) * 32;
    const float4* src = (const float4*)(weight + (size_t)c * C_IN + kh);
#pragma unroll
    for (int q = 0; q < 8; q++) {
      float4 v = src[q];
      int k = kh + q * 4;
      wl[(k + 0) * C_OUT + c] = v.x;
      wl[(k + 1) * C_OUT + c] = v.y;
      wl[(k + 2) * C_OUT + c] = v.z;
      wl[(k + 3) * C_OUT + c] = v.w;
    }
  }
  float breg[8];
#pragma unroll
  for (int j = 0; j < 8; j++) breg[j] = bias[cg * 8 + j];

  const int ntile = (n + TPTS - 1) / TPTS;
  for (int t = blockIdx.x; t < ntile; t += gridDim.x) {
    const int base = t * TPTS;
    __syncthreads();  // protect LDS from previous tile readers
    // stage feat transposed: thread owns p=tid>>1, k-half=(tid&1)*32
    {
      int p = tid >> 1;
      int kh = (tid & 1) * 32;
      int gp = base + p;
      if (gp < n) {
        const float4* src = (const float4*)(feat + (size_t)gp * C_IN + kh);
#pragma unroll
        for (int q = 0; q < 8; q++) {
          float4 v = src[q];
          int k = kh + q * 4;
          fl[(k + 0) * TPTS + p] = v.x;
          fl[(k + 1) * TPTS + p] = v.y;
          fl[(k + 2) * TPTS + p] = v.z;
          fl[(k + 3) * TPTS + p] = v.w;
        }
      } else {
#pragma unroll
        for (int q = 0; q < 32; q++) fl[(kh + q) * TPTS + p] = 0.f;
      }
      if (tid < TPTS) ldsC[tid] = (base + tid < n) ? cluster[base + tid] : 0x80000000u;
    }
    __syncthreads();

    float acc[8][8];
#pragma unroll
    for (int i = 0; i < 8; i++)
#pragma unroll
      for (int j = 0; j < 8; j++) acc[i][j] = 0.f;

#pragma unroll 2
    for (int k = 0; k < C_IN; k++) {
      float4 f0 = *(const float4*)(fl + k * TPTS + pg * 8);
      float4 f1 = *(const float4*)(fl + k * TPTS + pg * 8 + 4);
      float4 w0 = *(const float4*)(wl + k * C_OUT + cg * 8);
      float4 w1 = *(const float4*)(wl + k * C_OUT + cg * 8 + 4);
      float fv[8] = {f0.x, f0.y, f0.z, f0.w, f1.x, f1.y, f1.z, f1.w};
      float wv[8] = {w0.x, w0.y, w0.z, w0.w, w1.x, w1.y, w1.z, w1.w};
#pragma unroll
      for (int i = 0; i < 8; i++)
#pragma unroll
        for (int j = 0; j < 8; j++) acc[i][j] = fmaf(fv[i], wv[j], acc[i][j]);
    }

    // writeout: 16 lanes (cg 0..15) cover one 512B point row contiguously
#pragma unroll
    for (int i = 0; i < 8; i++) {
      int p = pg * 8 + i;
      u32 cl = ldsC[p];
      if (cl & 0x80000000u) continue;  // multi-point (k8) or tail
      float4 o0 = {acc[i][0] + breg[0], acc[i][1] + breg[1],
                   acc[i][2] + breg[2], acc[i][3] + breg[3]};
      float4 o1 = {acc[i][4] + breg[4], acc[i][5] + breg[5],
                   acc[i][6] + breg[6], acc[i][7] + breg[7]};
      float4* dst = (float4*)(out_feat + (size_t)cl * C_OUT + cg * 8);
      dst[0] = o0;
      dst[1] = o1;
    }
  }
}

// ---------- K7: counts, coord means, invalid-tail zeros ----------
__global__ void k7_finalize(const u64* __restrict__ pairs, const u32* __restrict__ segStart,
                            const u32* __restrict__ meta, const float* __restrict__ coord,
                            float* __restrict__ out_feat, float* __restrict__ out_coord,
                            float* __restrict__ out_grid, float* __restrict__ out_batch,
                            float* __restrict__ out_counts, int n) {
  int t = blockIdx.x * blockDim.x + threadIdx.x;
  if (t >= n) return;
  u32 numSeg = meta[0];
  if ((u32)t < numSeg) {
    u32 st = segStart[t], en = segStart[t + 1];
    u32 cnt = en - st;
    out_counts[t] = (float)cnt;
    float sx = 0.f, sy = 0.f, sz = 0.f;
    for (u32 e = st; e < en; e++) {
      u32 idx = (u32)(pairs[e] & 0xFFFFFFFFu);
      sx += coord[(size_t)idx * 3 + 0];
      sy += coord[(size_t)idx * 3 + 1];
      sz += coord[(size_t)idx * 3 + 2];
    }
    float fc = (float)cnt;
    out_coord[(size_t)t * 3 + 0] = sx / fc;
    out_coord[(size_t)t * 3 + 1] = sy / fc;
    out_coord[(size_t)t * 3 + 2] = sz / fc;
  } else {
    out_counts[t] = 0.f;
    out_batch[t] = 0.f;
    out_coord[(size_t)t * 3 + 0] = 0.f;
    out_coord[(size_t)t * 3 + 1] = 0.f;
    out_coord[(size_t)t * 3 + 2] = 0.f;
    out_grid[(size_t)t * 3 + 0] = 0.f;
    out_grid[(size_t)t * 3 + 1] = 0.f;
    out_grid[(size_t)t * 3 + 2] = 0.f;
    for (int c = 0; c < C_OUT; c++) out_feat[(size_t)t * C_OUT + c] = 0.f;
  }
}

// ---------- K8: multi-point clusters — parallel matmul + max (1 block/cluster) ----------
__global__ __launch_bounds__(128) void k8_multi(
    const u64* __restrict__ pairs, const u32* __restrict__ segStart,
    const u32* __restrict__ meta, const u32* __restrict__ multiList,
    const float* __restrict__ feat, const float* __restrict__ weight,
    const float* __restrict__ bias, float* __restrict__ out_feat) {
  __shared__ float ldsF[C_IN];
  const int c = threadIdx.x;  // one output channel per thread (128 threads)
  float wreg[C_IN];
  const float4* wrow = (const float4*)(weight + (size_t)c * C_IN);
#pragma unroll
  for (int q = 0; q < 16; q++) {
    float4 v = wrow[q];
    wreg[4 * q] = v.x; wreg[4 * q + 1] = v.y; wreg[4 * q + 2] = v.z; wreg[4 * q + 3] = v.w;
  }
  const float bc = bias[c];
  const u32 nm = meta[1];
  for (u32 m = blockIdx.x; m < nm; m += gridDim.x) {
    u32 seg = multiList[m];
    u32 st = segStart[seg], en = segStart[seg + 1];
    float mx = -3.4e38f;
    for (u32 e = st; e < en; e++) {
      u32 idx = (u32)(pairs[e] & 0xFFFFFFFFu);
      __syncthreads();
      if (c < 16) ((float4*)ldsF)[c] = ((const float4*)(feat + (size_t)idx * C_IN))[c];
      __syncthreads();
      float d = bc;
#pragma unroll
      for (int q = 0; q < 16; q++) {
        float4 v = ((const float4*)ldsF)[q];
        d = fmaf(v.x, wreg[4 * q], d);
        d = fmaf(v.y, wreg[4 * q + 1], d);
        d = fmaf(v.z, wreg[4 * q + 2], d);
        d = fmaf(v.w, wreg[4 * q + 3], d);
      }
      mx = fmaxf(mx, d);
    }
    out_feat[(size_t)seg * C_OUT + c] = mx;
  }
}

extern "C" void kernel_launch(void* const* d_in, const int* in_sizes, int n_in,
                              void* d_out, int out_size, void* d_ws, size_t ws_size,
                              hipStream_t stream) {
  const float* feat = (const float*)d_in[0];
  const float* coord = (const float*)d_in[1];
  const float* weight = (const float*)d_in[2];
  const float* bias = (const float*)d_in[3];
  const int* grid = (const int*)d_in[4];
  const int* batch = (const int*)d_in[5];
  const int* stride = (const int*)d_in[6];
  const int n = in_sizes[0] / C_IN;

  float* out_feat = (float*)d_out;
  float* out_coord = out_feat + (size_t)n * C_OUT;
  float* out_grid = out_coord + (size_t)n * 3;
  float* out_batch = out_grid + (size_t)n * 3;
  float* out_counts = out_batch + n;

  u32* W = (u32*)d_ws;
  u32* hist = W;                   // 65536
  u32* cursor = W + 65536;         // 65536
  u32* off = W + 131072;           // 65537
  u32* meta = W + 196864;          // [0]=numSeg [1]=numMulti
  u32* blockCnt = W + 196992;      // up to 2048
  u32* blockBase = W + 199040;     // up to 2048
  u32* multiList = W + 201088;     // up to 65536 entries
  u32* keys = W + 270336;          // n
  u32* cluster = keys + n;         // n
  u32* segStart = cluster + n;     // n+1
  size_t pe = 270336 + 3 * (size_t)n + 2;
  pe &= ~(size_t)1;                // 8-byte align for u64
  u64* pairs = (u64*)(W + pe);     // n

  int nb = (n + 255) / 256;
  k0_zero<<<NBUCK / 4 / 256, 256, 0, stream>>>((uint4*)hist);
  k1_keys<<<nb, 256, 0, stream>>>(grid, batch, stride, n, keys, hist);
  k2_scan<<<1, 1024, 0, stream>>>(hist, off, cursor);
  k3_scatter<<<nb, 256, 0, stream>>>(keys, cursor, pairs, n);
  k4_sort<<<NBUCK / 4, 256, 0, stream>>>(pairs, off);  // one wave per bucket
  int nb5 = (n + 4095) / 4096;
  k5a_count<<<nb5, 256, 0, stream>>>(pairs, n, blockCnt);
  k5b_scanblocks<<<1, 256, 0, stream>>>(blockCnt, nb5, blockBase, meta, segStart, n);
  k5c_assign<<<nb5, 256, 0, stream>>>(pairs, n, blockBase, segStart, cluster, out_grid, out_batch,
                                      meta, multiList);
  k6_gemm<<<2048, 256, 0, stream>>>(feat, weight, bias, cluster, out_feat, n);
  k7_finalize<<<nb, 256, 0, stream>>>(pairs, segStart, meta, coord, out_feat, out_coord,
                                      out_grid, out_batch, out_counts, n);
  k8_multi<<<1024, 128, 0, stream>>>(pairs, segStart, meta, multiList, feat, weight, bias, out_feat);
}